// Round 13
// baseline (436.211 us; speedup 1.0000x reference)
//
#include <hip/hip_runtime.h>
#include <hip/hip_bf16.h>

// ---------- problem constants ----------
#define N_NODES 50000
#define N_EDGES 800000
#define C_DIM   256      // IN_C == HID_C
#define OUT_C   128
#define N_GRAPHS 256

typedef unsigned short ushort8 __attribute__((ext_vector_type(8)));
typedef __bf16         bf16x8  __attribute__((ext_vector_type(8)));
typedef float          f32x4   __attribute__((ext_vector_type(4)));

typedef __attribute__((address_space(1))) const unsigned int gu32;
typedef __attribute__((address_space(3))) unsigned int lu32;

#if __has_builtin(__builtin_amdgcn_sched_barrier)
#define SCHED_FENCE() __builtin_amdgcn_sched_barrier(0)
#else
#define SCHED_FENCE() ((void)0)
#endif

__device__ __forceinline__ float us2f(unsigned short u) {
    unsigned int x = ((unsigned int)u) << 16;
    return __builtin_bit_cast(float, x);
}
__device__ __forceinline__ unsigned short f2bf(float f) {
    unsigned int u = __builtin_bit_cast(unsigned int, f);
    u += 0x7fffu + ((u >> 16) & 1u);   // RNE
    return (unsigned short)(u >> 16);
}

__device__ __forceinline__ int lower_bound_i(const int* __restrict__ a, int n, int v) {
    int lo = 0, hi = n;
    while (lo < hi) {
        int mid = (lo + hi) >> 1;
        if (a[mid] < v) lo = mid + 1; else hi = mid;
    }
    return lo;
}

// ---------- K1: merged preprocess (r12, unchanged) ----------
__global__ void preprocess(const float* __restrict__ x, unsigned short* __restrict__ xb,
                           const float* __restrict__ W0, const float* __restrict__ W1,
                           const float* __restrict__ W2, const float* __restrict__ W3,
                           unsigned short* __restrict__ D0, unsigned short* __restrict__ D1,
                           unsigned short* __restrict__ D2, unsigned short* __restrict__ D3,
                           const int* __restrict__ dst, const int* __restrict__ batch,
                           int* __restrict__ row_ptr, int* __restrict__ graph_ptr,
                           float* __restrict__ inv_deg) {
    __shared__ float tile[64][65];
    int b = blockIdx.x;
    int t = threadIdx.x;
    if (b < 12500) {
        int i = b * 256 + t;                 // group of 4 elements
        float4 v = *(const float4*)(x + ((size_t)i << 2));
        ushort4 o;
        o.x = f2bf(v.x); o.y = f2bf(v.y); o.z = f2bf(v.z); o.w = f2bf(v.w);
        *(ushort4*)(xb + ((size_t)i << 2)) = o;
    } else if (b < 12564) {
        int b2 = b - 12500;                  // 0..63: 4 matrices x 16 tiles
        const float* S; unsigned short* D;
        switch (b2 >> 4) {
            case 0: S = W0; D = D0; break;
            case 1: S = W1; D = D1; break;
            case 2: S = W2; D = D2; break;
            default: S = W3; D = D3; break;
        }
        int tl = b2 & 15;
        int kt = (tl >> 2) * 64, nt = (tl & 3) * 64;
#pragma unroll
        for (int j = 0; j < 16; ++j) {
            int idx = t + j * 256;
            int r = idx >> 6, c = idx & 63;
            tile[r][c] = S[(size_t)(kt + r) * 256 + nt + c];
        }
        __syncthreads();
#pragma unroll
        for (int j = 0; j < 16; ++j) {
            int idx = t + j * 256;
            int r = idx >> 6, c = idx & 63;
            D[(size_t)(nt + r) * 256 + kt + c] = f2bf(tile[c][r]);
        }
    } else {
        int i = (b - 12564) * 256 + t;
        if (i <= N_NODES) {
            int lb = lower_bound_i(dst, N_EDGES, i);
            row_ptr[i] = lb;
            if (i < N_NODES) {
                int ub = lower_bound_i(dst, N_EDGES, i + 1);
                int cnt = ub - lb;
                inv_deg[i] = (cnt > 0) ? (1.0f / (float)cnt) : 0.0f;
            }
        }
        if (i <= N_GRAPHS) graph_ptr[i] = lower_bound_i(batch, N_NODES, i);
    }
}

// ---------- K2: XCD-sliced mean aggregation ----------
// Channel dim split into 8 slices of 32 ch (64 B = one cache line per
// node-row-slice). Block b: slice = b&7, node-group = b>>3. Under round-robin
// blockIdx->XCD dispatch, slice j pins to XCD j -> per-XCD x-footprint 3.2 MB
// fits the 4 MB private L2 (prior layout: 25.6 MB in 4 MB -> 175 MB of L2
// misses = the 57 µs ceiling of rounds 3-12). Correctness is mapping-
// independent. Wave: lane = eg*8+cq (eg: edge subgroup, cq: channel quad);
// 8 edges/wave-load, unroll 4 = 32 edges in flight; shfl_xor butterfly folds
// the 8 edge subgroups; lanes eg==0 store one aligned 64B line.
__global__ void aggregate(const unsigned short* __restrict__ X,
                          const int* __restrict__ src,
                          const int* __restrict__ row_ptr,
                          const float* __restrict__ inv_deg,
                          unsigned short* __restrict__ out) {
    int b     = blockIdx.x;
    int slice = b & 7;
    int wid   = threadIdx.x >> 6, lane = threadIdx.x & 63;
    int gw    = (b >> 3) * 4 + wid;
    if (gw >= N_NODES) return;
    int eg = lane >> 3;                     // 0..7 edge subgroup
    int cq = lane & 7;                      // 0..7 channel quad
    int choff = slice * 32 + cq * 4;

    int e0 = row_ptr[gw], e1 = row_ptr[gw + 1];
    float a0 = 0.f, a1 = 0.f, a2 = 0.f, a3 = 0.f;
    int e = e0;

    for (; e + 32 <= e1; e += 32) {         // 32 edges in flight
        ushort4 v[4];
#pragma unroll
        for (int j = 0; j < 4; ++j) {
            int s = src[e + j * 8 + eg];
            v[j] = *(const ushort4*)(X + (size_t)s * 256 + choff);
        }
        SCHED_FENCE();
#pragma unroll
        for (int j = 0; j < 4; ++j) {
            a0 += us2f(v[j].x); a1 += us2f(v[j].y);
            a2 += us2f(v[j].z); a3 += us2f(v[j].w);
        }
    }
    if (e < e1) {                            // clamped epilogue (<=32 edges)
        int cl = e1 - 1;
        ushort4 v[4]; float w[4];
#pragma unroll
        for (int j = 0; j < 4; ++j) {
            int ej = e + j * 8 + eg;
            int ec = ej < cl ? ej : cl;
            w[j] = (ej < e1) ? 1.0f : 0.0f;
            int s = src[ec];
            v[j] = *(const ushort4*)(X + (size_t)s * 256 + choff);
        }
        SCHED_FENCE();
#pragma unroll
        for (int j = 0; j < 4; ++j) {
            a0 = fmaf(us2f(v[j].x), w[j], a0);
            a1 = fmaf(us2f(v[j].y), w[j], a1);
            a2 = fmaf(us2f(v[j].z), w[j], a2);
            a3 = fmaf(us2f(v[j].w), w[j], a3);
        }
    }

    // fold the 8 edge subgroups (lane masks 8,16,32)
#pragma unroll
    for (int m = 8; m <= 32; m <<= 1) {
        a0 += __shfl_xor(a0, m, 64);
        a1 += __shfl_xor(a1, m, 64);
        a2 += __shfl_xor(a2, m, 64);
        a3 += __shfl_xor(a3, m, 64);
    }

    if (eg == 0) {
        float sc = inv_deg[gw];
        ushort4 o;
        o.x = f2bf(a0 * sc); o.y = f2bf(a1 * sc);
        o.z = f2bf(a2 * sc); o.w = f2bf(a3 * sc);
        *(ushort4*)(out + (size_t)gw * 256 + choff) = o;
    }
}

// ---------- K3: fused SAGE GEMM (round-6/9 shape — measured best, UNCHANGED) ----------
__global__ __launch_bounds__(512, 2)
void gemm_fused(const unsigned short* __restrict__ A1,
                const unsigned short* __restrict__ A2,
                const unsigned short* __restrict__ B1t,
                const unsigned short* __restrict__ B2t,
                const float* __restrict__ bias,
                unsigned short* __restrict__ C,
                int M, int do_relu) {
    __shared__ __align__(16) unsigned short As[8192];   // 128 rows x 8 chunks x 8
    __shared__ __align__(16) unsigned short Bs[16384];  // 256 rows x 8 chunks x 8

    const int t    = threadIdx.x;
    const int m0   = blockIdx.x * 128;
    const int lane = t & 63, wid = t >> 6;
    const int wm   = (wid >> 2) * 64;       // {0,64}
    const int wn   = (wid & 3) * 64;        // {0,64,128,192}
    const int lrow = lane & 15;
    const int kq   = lane >> 4;             // 0..3

    const f32x4 zero4 = {0.f, 0.f, 0.f, 0.f};
    f32x4 acc[4][4];
#pragma unroll
    for (int i = 0; i < 4; ++i)
#pragma unroll
        for (int j = 0; j < 4; ++j) acc[i][j] = zero4;

    for (int it = 0; it < 8; ++it) {        // K = 512 virtual (2 x 256), BK = 64
        const unsigned short* __restrict__ Ab = (it < 4) ? A1 : A2;
        const unsigned short* __restrict__ Bb = (it < 4) ? B1t : B2t;
        int ko = (it * 64) & 255;

#pragma unroll
        for (int i = 0; i < 2; ++i) {
            int q   = t + i * 512;          // 0..1023
            int row = q >> 3;
            int kb  = (q & 7) ^ (row & 7);
            const unsigned short* ga = Ab + (size_t)(m0 + row) * 256 + ko + kb * 8;
            __builtin_amdgcn_global_load_lds((gu32*)ga, (lu32*)(As + q * 8), 16, 0, 0);
        }
#pragma unroll
        for (int i = 0; i < 4; ++i) {
            int q   = t + i * 512;          // 0..2047
            int row = q >> 3;
            int kb  = (q & 7) ^ (row & 7);
            const unsigned short* gb = Bb + (size_t)row * 256 + ko + kb * 8;
            __builtin_amdgcn_global_load_lds((gu32*)gb, (lu32*)(Bs + q * 8), 16, 0, 0);
        }
        __syncthreads();

#pragma unroll
        for (int s = 0; s < 2; ++s) {       // two 32-k MFMA steps per BK=64
            int kqp = s * 4 + kq;
            bf16x8 af[4], bfr[4];
#pragma unroll
            for (int mi = 0; mi < 4; ++mi) {
                int r = wm + mi * 16 + lrow;
                int slot = r * 8 + (kqp ^ (lrow & 7));
                uint4 u = *(const uint4*)(As + slot * 8);
                af[mi] = __builtin_bit_cast(bf16x8, u);
            }
#pragma unroll
            for (int ni = 0; ni < 4; ++ni) {
                int r = wn + ni * 16 + lrow;
                int slot = r * 8 + (kqp ^ (lrow & 7));
                uint4 u = *(const uint4*)(Bs + slot * 8);
                bfr[ni] = __builtin_bit_cast(bf16x8, u);
            }
#pragma unroll
            for (int mi = 0; mi < 4; ++mi)
#pragma unroll
                for (int ni = 0; ni < 4; ++ni)
                    acc[mi][ni] = __builtin_amdgcn_mfma_f32_16x16x32_bf16(
                        af[mi], bfr[ni], acc[mi][ni], 0, 0, 0);
        }
        __syncthreads();
    }

    // epilogue: D mapping col = lane&15, row = (lane>>4)*4 + reg
    const int rbase = (lane >> 4) * 4;
#pragma unroll
    for (int ni = 0; ni < 4; ++ni) {
        int n  = wn + ni * 16 + lrow;
        float bv = bias[n];
#pragma unroll
        for (int mi = 0; mi < 4; ++mi) {
            int mb = m0 + wm + mi * 16 + rbase;
#pragma unroll
            for (int r = 0; r < 4; ++r) {
                int m = mb + r;
                if (m < M) {
                    float v = acc[mi][ni][r] + bv;
                    if (do_relu) v = fmaxf(v, 0.f);
                    C[(size_t)m * 256 + n] = f2bf(v);
                }
            }
        }
    }
}

// ---------- K4: fused pool + root gather + final linear (r12, unchanged) ----------
__global__ void pool_final(const unsigned short* __restrict__ h2,
                           const float* __restrict__ p,
                           const int* __restrict__ graph_ptr,
                           const int* __restrict__ root_ptr,
                           const float* __restrict__ Wlin,
                           const float* __restrict__ blin,
                           float* __restrict__ out) {
    __shared__ float part[2][256];
    __shared__ float fl[512];
    int g = blockIdx.x;
    int t = threadIdx.x;        // 512 threads
    int c = t & 255;            // channel
    int half = t >> 8;          // 0 or 1
    int s = graph_ptr[g], e = graph_ptr[g + 1];
    int mid = s + ((e - s) >> 1);
    int lo0 = half ? mid : s;
    int hi0 = half ? e : mid;

    float acc = 0.f;
    for (int n = lo0; n < hi0; n += 8) {
        int cl = hi0 - 1;
        float w[8]; unsigned short v[8];
#pragma unroll
        for (int j = 0; j < 8; ++j) {
            int nj = n + j;
            int ncj = nj < cl ? nj : cl;
            int nu = __builtin_amdgcn_readfirstlane(ncj);
            w[j] = (nj < hi0) ? p[nu] : 0.0f;
            v[j] = h2[(size_t)nu * 256 + c];
        }
        SCHED_FENCE();
#pragma unroll
        for (int j = 0; j < 8; ++j)
            acc = fmaf(us2f(v[j]), w[j], acc);
    }
    part[half][c] = acc;
    __syncthreads();

    if (half == 0) {
        float cnt = (float)(e - s);
        int root = root_ptr[g];
        fl[c]       = us2f(h2[(size_t)root * 256 + c]);
        fl[256 + c] = (part[0][c] + part[1][c]) / fmaxf(cnt, 1.0f);
    }
    __syncthreads();

    if (t < 128) {
        int o = t;
        float s0 = 0.f, s1 = 0.f, s2 = 0.f, s3 = 0.f;
        for (int k = 0; k < 512; k += 4) {
            s0 = fmaf(fl[k + 0], Wlin[(k + 0) * 128 + o], s0);
            s1 = fmaf(fl[k + 1], Wlin[(k + 1) * 128 + o], s1);
            s2 = fmaf(fl[k + 2], Wlin[(k + 2) * 128 + o], s2);
            s3 = fmaf(fl[k + 3], Wlin[(k + 3) * 128 + o], s3);
        }
        out[(size_t)g * 128 + o] = blin[o] + ((s0 + s1) + (s2 + s3));
    }
}

extern "C" void kernel_launch(void* const* d_in, const int* in_sizes, int n_in,
                              void* d_out, int out_size, void* d_ws, size_t ws_size,
                              hipStream_t stream) {
    const float* x        = (const float*)d_in[0];
    const int*   src      = (const int*)d_in[1];
    const int*   dst      = (const int*)d_in[2];
    const float* p        = (const float*)d_in[3];
    const int*   batch    = (const int*)d_in[4];
    const int*   root_ptr = (const int*)d_in[5];
    // d_in[6] = num_graphs (256, hard-coded)
    const float* Wl1  = (const float*)d_in[7];
    const float* Wr1  = (const float*)d_in[8];
    const float* b1   = (const float*)d_in[9];
    const float* Wl2  = (const float*)d_in[10];
    const float* Wr2  = (const float*)d_in[11];
    const float* b2   = (const float*)d_in[12];
    const float* Wlin = (const float*)d_in[13];
    const float* blin = (const float*)d_in[14];
    float* out = (float*)d_out;

    // workspace layout (256B aligned slabs); h2 aliases xb (dead after gemm1)
    size_t off = 0;
    char* base = (char*)d_ws;
    auto alloc = [&](size_t bytes) -> void* {
        void* q = base + off;
        off += (bytes + 255) & ~(size_t)255;
        return q;
    };
    int*            row_ptr   = (int*)  alloc((N_NODES + 1) * sizeof(int));
    int*            graph_ptr = (int*)  alloc((N_GRAPHS + 1) * sizeof(int));
    float*          inv_deg   = (float*)alloc(N_NODES * sizeof(float));
    unsigned short* Wl1t = (unsigned short*)alloc(256 * 256 * 2);
    unsigned short* Wr1t = (unsigned short*)alloc(256 * 256 * 2);
    unsigned short* Wl2t = (unsigned short*)alloc(256 * 256 * 2);
    unsigned short* Wr2t = (unsigned short*)alloc(256 * 256 * 2);
    unsigned short* xb   = (unsigned short*)alloc((size_t)N_NODES * 256 * 2);
    unsigned short* aggb = (unsigned short*)alloc((size_t)N_NODES * 256 * 2);
    unsigned short* h1   = (unsigned short*)alloc((size_t)N_NODES * 256 * 2);
    unsigned short* h2   = xb;   // xb dead after gemm1
    (void)ws_size; (void)n_in; (void)in_sizes; (void)out_size;

    preprocess<<<12760, 256, 0, stream>>>(x, xb, Wl1, Wr1, Wl2, Wr2,
                                          Wl1t, Wr1t, Wl2t, Wr2t,
                                          dst, batch, row_ptr, graph_ptr, inv_deg);

    dim3 ggrid((N_NODES + 127) / 128);
    int agrid = ((N_NODES + 3) / 4) * 8;    // 8 channel slices x node-groups

    // conv1: h1 = relu(agg(x)@Wl1 + x@Wr1 + b1)
    aggregate<<<agrid, 256, 0, stream>>>(xb, src, row_ptr, inv_deg, aggb);
    gemm_fused<<<ggrid, 512, 0, stream>>>(aggb, xb, Wl1t, Wr1t, b1, h1, N_NODES, 1);

    // conv2: h2 = agg(h1)@Wl2 + h1@Wr2 + b2
    aggregate<<<agrid, 256, 0, stream>>>(h1, src, row_ptr, inv_deg, aggb);
    gemm_fused<<<ggrid, 512, 0, stream>>>(aggb, h1, Wl2t, Wr2t, b2, h2, N_NODES, 0);

    // fused pool + root gather + final linear
    pool_final<<<N_GRAPHS, 512, 0, stream>>>(h2, p, graph_ptr, root_ptr,
                                             Wlin, blin, out);
}

// Round 14
// 316.479 us; speedup vs baseline: 1.3783x; 1.3783x over previous
//
#include <hip/hip_runtime.h>
#include <hip/hip_bf16.h>

// ---------- problem constants ----------
#define N_NODES 50000
#define N_EDGES 800000
#define C_DIM   256      // IN_C == HID_C
#define OUT_C   128
#define N_GRAPHS 256

typedef unsigned short ushort8 __attribute__((ext_vector_type(8)));
typedef __bf16         bf16x8  __attribute__((ext_vector_type(8)));
typedef float          f32x4   __attribute__((ext_vector_type(4)));

typedef __attribute__((address_space(1))) const unsigned int gu32;
typedef __attribute__((address_space(3))) unsigned int lu32;

#if __has_builtin(__builtin_amdgcn_sched_barrier)
#define SCHED_FENCE() __builtin_amdgcn_sched_barrier(0)
#else
#define SCHED_FENCE() ((void)0)
#endif

__device__ __forceinline__ float us2f(unsigned short u) {
    unsigned int x = ((unsigned int)u) << 16;
    return __builtin_bit_cast(float, x);
}
__device__ __forceinline__ unsigned short f2bf(float f) {
    unsigned int u = __builtin_bit_cast(unsigned int, f);
    u += 0x7fffu + ((u >> 16) & 1u);   // RNE
    return (unsigned short)(u >> 16);
}

__device__ __forceinline__ int lower_bound_i(const int* __restrict__ a, int n, int v) {
    int lo = 0, hi = n;
    while (lo < hi) {
        int mid = (lo + hi) >> 1;
        if (a[mid] < v) lo = mid + 1; else hi = mid;
    }
    return lo;
}

// ---------- K1: merged preprocess ----------
// blocks [0,12500): convert x f32->bf16 (4 elems/thread)
// blocks [12500,12564): LDS-tiled transpose+convert of the 4 weights
// blocks [12564,12760): CSR row_ptr/graph_ptr/inv_deg
__global__ void preprocess(const float* __restrict__ x, unsigned short* __restrict__ xb,
                           const float* __restrict__ W0, const float* __restrict__ W1,
                           const float* __restrict__ W2, const float* __restrict__ W3,
                           unsigned short* __restrict__ D0, unsigned short* __restrict__ D1,
                           unsigned short* __restrict__ D2, unsigned short* __restrict__ D3,
                           const int* __restrict__ dst, const int* __restrict__ batch,
                           int* __restrict__ row_ptr, int* __restrict__ graph_ptr,
                           float* __restrict__ inv_deg) {
    __shared__ float tile[64][65];
    int b = blockIdx.x;
    int t = threadIdx.x;
    if (b < 12500) {
        int i = b * 256 + t;                 // group of 4 elements
        float4 v = *(const float4*)(x + ((size_t)i << 2));
        ushort4 o;
        o.x = f2bf(v.x); o.y = f2bf(v.y); o.z = f2bf(v.z); o.w = f2bf(v.w);
        *(ushort4*)(xb + ((size_t)i << 2)) = o;
    } else if (b < 12564) {
        int b2 = b - 12500;                  // 0..63: 4 matrices x 16 tiles
        const float* S; unsigned short* D;
        switch (b2 >> 4) {
            case 0: S = W0; D = D0; break;
            case 1: S = W1; D = D1; break;
            case 2: S = W2; D = D2; break;
            default: S = W3; D = D3; break;
        }
        int tl = b2 & 15;
        int kt = (tl >> 2) * 64, nt = (tl & 3) * 64;
#pragma unroll
        for (int j = 0; j < 16; ++j) {       // coalesced read of S[kt.., nt..]
            int idx = t + j * 256;
            int r = idx >> 6, c = idx & 63;
            tile[r][c] = S[(size_t)(kt + r) * 256 + nt + c];
        }
        __syncthreads();
#pragma unroll
        for (int j = 0; j < 16; ++j) {       // coalesced write of D[nt.., kt..]
            int idx = t + j * 256;
            int r = idx >> 6, c = idx & 63;
            D[(size_t)(nt + r) * 256 + kt + c] = f2bf(tile[c][r]);
        }
    } else {
        int i = (b - 12564) * 256 + t;
        if (i <= N_NODES) {
            int lb = lower_bound_i(dst, N_EDGES, i);
            row_ptr[i] = lb;
            if (i < N_NODES) {
                int ub = lower_bound_i(dst, N_EDGES, i + 1);
                int cnt = ub - lb;
                inv_deg[i] = (cnt > 0) ? (1.0f / (float)cnt) : 0.0f;
            }
        }
        if (i <= N_GRAPHS) graph_ptr[i] = lower_bound_i(batch, N_NODES, i);
    }
}

// ---------- K2: mean aggregation (bf16 in/out, f32 accum) ----------
// AT STRUCTURAL CEILING (rounds 3-13: six structures; this one = 57 µs,
// 175 MB random 64B-line L2-miss traffic @ ~3.6 TB/s. XCD channel-slicing
// (r13) regressed 2.3x — blockIdx%8 does not localize slices to XCD L2s).
// One wave per node, scalar-base gathers, 16-deep fenced bursts.
__global__ void aggregate(const unsigned short* __restrict__ X,
                          const int* __restrict__ src,
                          const int* __restrict__ row_ptr,
                          const float* __restrict__ inv_deg,
                          unsigned short* __restrict__ out) {
    int gw   = (blockIdx.x * blockDim.x + threadIdx.x) >> 6;
    int lane = threadIdx.x & 63;
    if (gw >= N_NODES) return;
    int e0 = row_ptr[gw], e1 = row_ptr[gw + 1];
    const int lo = lane << 2;
    float a0 = 0.f, a1 = 0.f, a2 = 0.f, a3 = 0.f;
    int e = e0;

    for (; e + 16 <= e1; e += 16) {
        ushort4 v[16];
#pragma unroll
        for (int j = 0; j < 16; ++j) {
            int s = __builtin_amdgcn_readfirstlane(src[e + j]);
            v[j] = *(const ushort4*)(X + ((size_t)s << 8) + lo);
        }
        SCHED_FENCE();
#pragma unroll
        for (int j = 0; j < 16; ++j) {
            a0 += us2f(v[j].x); a1 += us2f(v[j].y);
            a2 += us2f(v[j].z); a3 += us2f(v[j].w);
        }
    }
    int rem = e1 - e;
    if (rem > 0) {
        int cl = e1 - 1;
        ushort4 v[16]; float w[16];
#pragma unroll
        for (int j = 0; j < 16; ++j) {
            int ej = e + j;
            int ec = ej < cl ? ej : cl;
            w[j] = (ej < e1) ? 1.0f : 0.0f;
            int s = __builtin_amdgcn_readfirstlane(src[ec]);
            v[j] = *(const ushort4*)(X + ((size_t)s << 8) + lo);
        }
        SCHED_FENCE();
#pragma unroll
        for (int j = 0; j < 16; ++j) {
            a0 = fmaf(us2f(v[j].x), w[j], a0);
            a1 = fmaf(us2f(v[j].y), w[j], a1);
            a2 = fmaf(us2f(v[j].z), w[j], a2);
            a3 = fmaf(us2f(v[j].w), w[j], a3);
        }
    }

    float sc = inv_deg[gw];
    ushort4 o;
    o.x = f2bf(a0 * sc); o.y = f2bf(a1 * sc); o.z = f2bf(a2 * sc); o.w = f2bf(a3 * sc);
    *(ushort4*)(out + ((size_t)gw << 8) + lo) = o;
}

// ---------- K3: fused SAGE GEMM (round-6/9 shape — measured best) ----------
// 128-row strip x FULL N=256; 512 thr = 8 waves (2m x 4n), 4x4 MFMA 16x16x32
// per wave, BK=64. Drain/compute balanced at ~2-3 blocks/CU; all reshapes
// (r7/r8/r10/r11) regressed.
__global__ __launch_bounds__(512, 2)
void gemm_fused(const unsigned short* __restrict__ A1,
                const unsigned short* __restrict__ A2,
                const unsigned short* __restrict__ B1t,
                const unsigned short* __restrict__ B2t,
                const float* __restrict__ bias,
                unsigned short* __restrict__ C,
                int M, int do_relu) {
    __shared__ __align__(16) unsigned short As[8192];   // 128 rows x 8 chunks x 8
    __shared__ __align__(16) unsigned short Bs[16384];  // 256 rows x 8 chunks x 8

    const int t    = threadIdx.x;
    const int m0   = blockIdx.x * 128;
    const int lane = t & 63, wid = t >> 6;
    const int wm   = (wid >> 2) * 64;       // {0,64}
    const int wn   = (wid & 3) * 64;        // {0,64,128,192}
    const int lrow = lane & 15;
    const int kq   = lane >> 4;             // 0..3

    const f32x4 zero4 = {0.f, 0.f, 0.f, 0.f};
    f32x4 acc[4][4];
#pragma unroll
    for (int i = 0; i < 4; ++i)
#pragma unroll
        for (int j = 0; j < 4; ++j) acc[i][j] = zero4;

    for (int it = 0; it < 8; ++it) {        // K = 512 virtual (2 x 256), BK = 64
        const unsigned short* __restrict__ Ab = (it < 4) ? A1 : A2;
        const unsigned short* __restrict__ Bb = (it < 4) ? B1t : B2t;
        int ko = (it * 64) & 255;

#pragma unroll
        for (int i = 0; i < 2; ++i) {
            int q   = t + i * 512;          // 0..1023
            int row = q >> 3;
            int kb  = (q & 7) ^ (row & 7);
            const unsigned short* ga = Ab + (size_t)(m0 + row) * 256 + ko + kb * 8;
            __builtin_amdgcn_global_load_lds((gu32*)ga, (lu32*)(As + q * 8), 16, 0, 0);
        }
#pragma unroll
        for (int i = 0; i < 4; ++i) {
            int q   = t + i * 512;          // 0..2047
            int row = q >> 3;
            int kb  = (q & 7) ^ (row & 7);
            const unsigned short* gb = Bb + (size_t)row * 256 + ko + kb * 8;
            __builtin_amdgcn_global_load_lds((gu32*)gb, (lu32*)(Bs + q * 8), 16, 0, 0);
        }
        __syncthreads();

#pragma unroll
        for (int s = 0; s < 2; ++s) {       // two 32-k MFMA steps per BK=64
            int kqp = s * 4 + kq;
            bf16x8 af[4], bfr[4];
#pragma unroll
            for (int mi = 0; mi < 4; ++mi) {
                int r = wm + mi * 16 + lrow;
                int slot = r * 8 + (kqp ^ (lrow & 7));
                uint4 u = *(const uint4*)(As + slot * 8);
                af[mi] = __builtin_bit_cast(bf16x8, u);
            }
#pragma unroll
            for (int ni = 0; ni < 4; ++ni) {
                int r = wn + ni * 16 + lrow;
                int slot = r * 8 + (kqp ^ (lrow & 7));
                uint4 u = *(const uint4*)(Bs + slot * 8);
                bfr[ni] = __builtin_bit_cast(bf16x8, u);
            }
#pragma unroll
            for (int mi = 0; mi < 4; ++mi)
#pragma unroll
                for (int ni = 0; ni < 4; ++ni)
                    acc[mi][ni] = __builtin_amdgcn_mfma_f32_16x16x32_bf16(
                        af[mi], bfr[ni], acc[mi][ni], 0, 0, 0);
        }
        __syncthreads();
    }

    // epilogue: D mapping col = lane&15, row = (lane>>4)*4 + reg
    const int rbase = (lane >> 4) * 4;
#pragma unroll
    for (int ni = 0; ni < 4; ++ni) {
        int n  = wn + ni * 16 + lrow;
        float bv = bias[n];
#pragma unroll
        for (int mi = 0; mi < 4; ++mi) {
            int mb = m0 + wm + mi * 16 + rbase;
#pragma unroll
            for (int r = 0; r < 4; ++r) {
                int m = mb + r;
                if (m < M) {
                    float v = acc[mi][ni][r] + bv;
                    if (do_relu) v = fmaxf(v, 0.f);
                    C[(size_t)m * 256 + n] = f2bf(v);
                }
            }
        }
    }
}

// ---------- K4: fused pool + root gather + final linear (512 thr: split range) ----------
__global__ void pool_final(const unsigned short* __restrict__ h2,
                           const float* __restrict__ p,
                           const int* __restrict__ graph_ptr,
                           const int* __restrict__ root_ptr,
                           const float* __restrict__ Wlin,
                           const float* __restrict__ blin,
                           float* __restrict__ out) {
    __shared__ float part[2][256];
    __shared__ float fl[512];
    int g = blockIdx.x;
    int t = threadIdx.x;        // 512 threads
    int c = t & 255;            // channel
    int half = t >> 8;          // 0 or 1
    int s = graph_ptr[g], e = graph_ptr[g + 1];
    int mid = s + ((e - s) >> 1);
    int lo0 = half ? mid : s;
    int hi0 = half ? e : mid;

    float acc = 0.f;
    for (int n = lo0; n < hi0; n += 8) {
        int cl = hi0 - 1;
        float w[8]; unsigned short v[8];
#pragma unroll
        for (int j = 0; j < 8; ++j) {
            int nj = n + j;
            int ncj = nj < cl ? nj : cl;
            int nu = __builtin_amdgcn_readfirstlane(ncj);
            w[j] = (nj < hi0) ? p[nu] : 0.0f;
            v[j] = h2[(size_t)nu * 256 + c];
        }
        SCHED_FENCE();
#pragma unroll
        for (int j = 0; j < 8; ++j)
            acc = fmaf(us2f(v[j]), w[j], acc);
    }
    part[half][c] = acc;
    __syncthreads();

    if (half == 0) {
        float cnt = (float)(e - s);
        int root = root_ptr[g];
        fl[c]       = us2f(h2[(size_t)root * 256 + c]);
        fl[256 + c] = (part[0][c] + part[1][c]) / fmaxf(cnt, 1.0f);
    }
    __syncthreads();

    if (t < 128) {
        int o = t;
        float s0 = 0.f, s1 = 0.f, s2 = 0.f, s3 = 0.f;
        for (int k = 0; k < 512; k += 4) {
            s0 = fmaf(fl[k + 0], Wlin[(k + 0) * 128 + o], s0);
            s1 = fmaf(fl[k + 1], Wlin[(k + 1) * 128 + o], s1);
            s2 = fmaf(fl[k + 2], Wlin[(k + 2) * 128 + o], s2);
            s3 = fmaf(fl[k + 3], Wlin[(k + 3) * 128 + o], s3);
        }
        out[(size_t)g * 128 + o] = blin[o] + ((s0 + s1) + (s2 + s3));
    }
}

extern "C" void kernel_launch(void* const* d_in, const int* in_sizes, int n_in,
                              void* d_out, int out_size, void* d_ws, size_t ws_size,
                              hipStream_t stream) {
    const float* x        = (const float*)d_in[0];
    const int*   src      = (const int*)d_in[1];
    const int*   dst      = (const int*)d_in[2];
    const float* p        = (const float*)d_in[3];
    const int*   batch    = (const int*)d_in[4];
    const int*   root_ptr = (const int*)d_in[5];
    // d_in[6] = num_graphs (256, hard-coded)
    const float* Wl1  = (const float*)d_in[7];
    const float* Wr1  = (const float*)d_in[8];
    const float* b1   = (const float*)d_in[9];
    const float* Wl2  = (const float*)d_in[10];
    const float* Wr2  = (const float*)d_in[11];
    const float* b2   = (const float*)d_in[12];
    const float* Wlin = (const float*)d_in[13];
    const float* blin = (const float*)d_in[14];
    float* out = (float*)d_out;

    // workspace layout (256B aligned slabs)
    size_t off = 0;
    char* base = (char*)d_ws;
    auto alloc = [&](size_t bytes) -> void* {
        void* q = base + off;
        off += (bytes + 255) & ~(size_t)255;
        return q;
    };
    int*            row_ptr   = (int*)  alloc((N_NODES + 1) * sizeof(int));
    int*            graph_ptr = (int*)  alloc((N_GRAPHS + 1) * sizeof(int));
    float*          inv_deg   = (float*)alloc(N_NODES * sizeof(float));
    unsigned short* Wl1t = (unsigned short*)alloc(256 * 256 * 2);
    unsigned short* Wr1t = (unsigned short*)alloc(256 * 256 * 2);
    unsigned short* Wl2t = (unsigned short*)alloc(256 * 256 * 2);
    unsigned short* Wr2t = (unsigned short*)alloc(256 * 256 * 2);
    unsigned short* xb   = (unsigned short*)alloc((size_t)N_NODES * 256 * 2);
    unsigned short* aggb = (unsigned short*)alloc((size_t)N_NODES * 256 * 2);
    unsigned short* h1   = (unsigned short*)alloc((size_t)N_NODES * 256 * 2);
    unsigned short* h2   = (unsigned short*)alloc((size_t)N_NODES * 256 * 2);
    (void)ws_size; (void)n_in; (void)in_sizes; (void)out_size;

    preprocess<<<12760, 256, 0, stream>>>(x, xb, Wl1, Wr1, Wl2, Wr2,
                                          Wl1t, Wr1t, Wl2t, Wr2t,
                                          dst, batch, row_ptr, graph_ptr, inv_deg);

    dim3 ggrid((N_NODES + 127) / 128);

    // conv1: h1 = relu(agg(x)@Wl1 + x@Wr1 + b1)
    aggregate<<<N_NODES / 4, 256, 0, stream>>>(xb, src, row_ptr, inv_deg, aggb);
    gemm_fused<<<ggrid, 512, 0, stream>>>(aggb, xb, Wl1t, Wr1t, b1, h1, N_NODES, 1);

    // conv2: h2 = agg(h1)@Wl2 + h1@Wr2 + b2
    aggregate<<<N_NODES / 4, 256, 0, stream>>>(h1, src, row_ptr, inv_deg, aggb);
    gemm_fused<<<ggrid, 512, 0, stream>>>(aggb, h1, Wl2t, Wr2t, b2, h2, N_NODES, 0);

    // fused pool + root gather + final linear
    pool_final<<<N_GRAPHS, 512, 0, stream>>>(h2, p, graph_ptr, root_ptr,
                                             Wlin, blin, out);
}